// Round 8
// baseline (258.545 us; speedup 1.0000x reference)
//
#include <hip/hip_runtime.h>

// Transposed flash attention, f16 MFMA (16x16x32), no-max softmax, split-K=2.
// R18: main loop UNCHANGED from R15/R17 (83.2us, verified twice; 825 TF ~
// within 8% of the m214 plain-HIP attn ceiling; 5 structural variants all
// null at 83-86us). New target: the rock-constant ~81us of non-main time
// (80.4/82.5/80.0/80.4/81.6 across R10-R17). attn_combine (3rd kernel,
// 4096 blocks, 50MB O round-trip + launch) is deleted and fused into the
// main kernel as a split-K fixup: after partial writes, all threads
// __threadfence() (release), thread0 atomicAdd(flag) ACQ_REL/AGENT scope;
// the SECOND finisher re-fences (acquire -> invalidates stale cross-XCD L2
// lines, Guideline 16) and combines its (b,qt) pair's 256 rows with math
// BIT-IDENTICAL to the old combine kernel. First finisher exits (frees CU);
// fixup overlaps other pairs' compute; no spin -> no deadlock; dispatch-
// order independent. flags (256 u32) zeroed via hipMemsetAsync in
// kernel_launch (graph-capturable; harness reset() uses it itself).
// Null read if total stays ~163: the 81us is harness-fixed -> refocus on
// 32x32-MFMA main-loop rework.
// launch_bounds(256,2) -- NEVER promise more (R9: 7x spill regression).

#define NBATCH 16
#define SEQ    4096
#define DIM    64
#define BQ     256
#define BK     64
#define NKT    (SEQ / BK)      // 64
#define KHALF  (NKT / 2)       // 32 tiles per key-half
#define OELEMS (NBATCH * SEQ * DIM)   // 4194304
#define NROWS  (NBATCH * SEQ)         // 65536
#define NTILES (NBATCH * NKT)         // 1024
#define TILEH  4096                   // halfs per 64x64 tile image (8 KB)
#define NPAIR  (NBATCH * (SEQ / BQ))  // 256 (b,qt) pairs

#define QSCALE 0.180336879f   // 0.125 * log2(e)

typedef _Float16 half2_t __attribute__((ext_vector_type(2)));
typedef _Float16 half4_t __attribute__((ext_vector_type(4)));
typedef _Float16 half8_t __attribute__((ext_vector_type(8)));
typedef float    floatx4 __attribute__((ext_vector_type(4)));

__device__ inline float fast_exp2(float x) {
#if __has_builtin(__builtin_amdgcn_exp2f)
  return __builtin_amdgcn_exp2f(x);
#else
  return exp2f(x);
#endif
}
__device__ inline float fast_rcp(float x) {
#if __has_builtin(__builtin_amdgcn_rcpf)
  return __builtin_amdgcn_rcpf(x);
#else
  return 1.0f / x;
#endif
}

// swizzled offset in halfs for element (row, col) of a 64x64 half tile
__device__ inline int swz(int row, int col) {
  return row * 64 + ((((col >> 3) ^ ((row >> 1) & 7)) << 3) | (col & 7));
}

// async 16B global->LDS copy: lds dest is wave-uniform; HW adds lane*16
__device__ inline void async16(const void* g, void* l) {
  __builtin_amdgcn_global_load_lds(
      (const __attribute__((address_space(1))) void*)g,
      (__attribute__((address_space(3))) void*)l, 16, 0, 0);
}

// ---------------- prepack: K,V f32 -> per-tile f16 LDS images ----------------
__global__ __launch_bounds__(256, 2)
void prepack_kv(const float* __restrict__ Kg, const float* __restrict__ Vg,
                _Float16* __restrict__ Kh, _Float16* __restrict__ Vh)
{
  __shared__ __align__(16) _Float16 sKi[TILEH];
  __shared__ __align__(16) _Float16 sVi[TILEH];
  const int tid = threadIdx.x;
  const int t16 = tid & 15;
  const int kg  = tid >> 4;
  const int bt  = blockIdx.x;                 // b*64 + kt
  const float* Kt_ = Kg + (size_t)bt * BK * DIM;
  const float* Vt_ = Vg + (size_t)bt * BK * DIM;

  floatx4 kbuf[4], vbuf[4];
  #pragma unroll
  for (int i = 0; i < 4; ++i) {
    const int key = kg + 16 * i;
    kbuf[i] = *(const floatx4*)(Kt_ + key * DIM + t16 * 4);
    vbuf[i] = *(const floatx4*)(Vt_ + key * DIM + t16 * 4);
  }
  #pragma unroll
  for (int i = 0; i < 4; ++i) {               // K: [key][dim] swizzled
    const int key = kg + 16 * i;
    half4_t h;
    #pragma unroll
    for (int j = 0; j < 4; ++j) h[j] = (_Float16)kbuf[i][j];
    *(half4_t*)&sKi[swz(key, t16 * 4)] = h;
  }
  {                                           // V: [dim][slot] swizzled
    const int vbase = (kg >> 2) * 8 + (kg & 3) * 2;
    #pragma unroll
    for (int e = 0; e < 4; ++e) {
      const int dim = t16 * 4 + e;
      half2_t h0; h0[0] = (_Float16)vbuf[0][e]; h0[1] = (_Float16)vbuf[1][e];
      half2_t h1; h1[0] = (_Float16)vbuf[2][e]; h1[1] = (_Float16)vbuf[3][e];
      *(half2_t*)&sVi[swz(dim, vbase)]      = h0;
      *(half2_t*)&sVi[swz(dim, vbase + 32)] = h1;
    }
  }
  __syncthreads();
  half8_t* Ko = (half8_t*)(Kh + (size_t)bt * TILEH);
  half8_t* Vo = (half8_t*)(Vh + (size_t)bt * TILEH);
  const half8_t* Ks = (const half8_t*)sKi;
  const half8_t* Vs = (const half8_t*)sVi;
  Ko[tid] = Ks[tid]; Ko[tid + 256] = Ks[tid + 256];
  Vo[tid] = Vs[tid]; Vo[tid + 256] = Vs[tid + 256];
}

// ---------------- main kernel ----------------
__global__ __launch_bounds__(256, 2)
void attn_f16_flash(const float* __restrict__ Qg, const _Float16* __restrict__ Kh,
                    const _Float16* __restrict__ Vh, float* __restrict__ O0g,
                    float* __restrict__ O1g, float* __restrict__ lsg,
                    unsigned int* __restrict__ flags)
{
  __shared__ __align__(16) _Float16 sT[4][2 * TILEH];  // ring: [buf][ K | V ]

  const int tid  = threadIdx.x;
  const int wave = tid >> 6;
  const int lane = tid & 63;
  const int l16  = lane & 15;
  const int quad = lane >> 4;
  const int hK   = (l16 >> 1) & 7;

  // XCD-clustered decode (bijective over 512 blocks): XCD x = bid&7 gets
  // batches {x, x+8} only -> 2MB K/V image working set per 4MB XCD L2.
  const int bid  = blockIdx.x;
  const int x    = bid & 7;
  const int r    = bid >> 3;                // 0..63
  const int b    = x + ((r & 1) << 3);
  const int qt   = (r >> 1) & 15;
  const int half = (r >> 5) & 1;
  const int q0   = qt * BQ + wave * 64;
  const int kt0  = half * KHALF;

  const float* Qb = Qg + ((size_t)b * SEQ + q0) * DIM;
  float*       Ob = (half ? O1g : O0g) + ((size_t)b * SEQ + q0) * DIM;
  float*       Ls = lsg + (size_t)half * NROWS + b * SEQ + q0;

  // ---- Q fragments (B-operand of S^T = K*Q^T), pre-scaled ----
  half8_t qf[4][2];
  #pragma unroll
  for (int s = 0; s < 4; ++s)
    #pragma unroll
    for (int c = 0; c < 2; ++c) {
      const floatx4 f0 = *(const floatx4*)(Qb + (s * 16 + l16) * DIM + c * 32 + quad * 8);
      const floatx4 f1 = *(const floatx4*)(Qb + (s * 16 + l16) * DIM + c * 32 + quad * 8 + 4);
      half8_t h;
      #pragma unroll
      for (int j = 0; j < 4; ++j) h[j] = (_Float16)(f0[j] * QSCALE);
      #pragma unroll
      for (int j = 0; j < 4; ++j) h[4 + j] = (_Float16)(f1[j] * QSCALE);
      qf[s][c] = h;
    }

  floatx4 oacc2[4][4];   // [dim-tile n][q-slab s]
  float   lsum2[4];
  #pragma unroll
  for (int n = 0; n < 4; ++n)
    #pragma unroll
    for (int s = 0; s < 4; ++s) oacc2[n][s] = (floatx4){0.f, 0.f, 0.f, 0.f};
  #pragma unroll
  for (int s = 0; s < 4; ++s) lsum2[s] = 0.f;

  // ---- async staging: 4 x 16B-per-lane copies per wave per tile ----
  #define ASYNC(KT, BUF)                                                       \
    do {                                                                       \
      const char* gk = (const char*)(Kh + ((size_t)b * NKT + (KT)) * TILEH)    \
                       + wave * 2048;                                          \
      const char* gv = (const char*)(Vh + ((size_t)b * NKT + (KT)) * TILEH)    \
                       + wave * 2048;                                          \
      char* lk = (char*)(&sT[BUF][0])     + wave * 2048;                       \
      char* lv = (char*)(&sT[BUF][TILEH]) + wave * 2048;                       \
      async16(gk + lane * 16,        lk);                                      \
      async16(gk + 1024 + lane * 16, lk + 1024);                               \
      async16(gv + lane * 16,        lv);                                      \
      async16(gv + 1024 + lane * 16, lv + 1024);                               \
    } while (0)

  // ---- QK^T of h-block H from ring buffer BUF into scX ----
  #define QKH(scX, BUF, H)                                                     \
    do {                                                                       \
      const _Float16* SKB = &sT[BUF][0];                                       \
      _Pragma("unroll")                                                        \
      for (int k2 = 0; k2 < 2; ++k2)                                           \
        _Pragma("unroll")                                                      \
        for (int s = 0; s < 4; ++s) scX[k2][s] = (floatx4){0.f, 0.f, 0.f, 0.f};\
      _Pragma("unroll")                                                        \
      for (int k2 = 0; k2 < 2; ++k2) {                                         \
        const int nk = (H) * 2 + k2;                                           \
        _Pragma("unroll")                                                      \
        for (int c = 0; c < 2; ++c) {                                          \
          half8_t kf = *(const half8_t*)&SKB[(nk * 16 + l16) * 64 +            \
                                             (((c * 4 + quad) ^ hK) << 3)];    \
          _Pragma("unroll")                                                    \
          for (int s = 0; s < 4; ++s)                                          \
            scX[k2][s] = __builtin_amdgcn_mfma_f32_16x16x32_f16(               \
                kf, qf[s][c], scX[k2][s], 0, 0, 0);                            \
        }                                                                      \
      }                                                                        \
    } while (0)

  // ---- softmax exp of scX -> bfrX (+ lsum) ----
  #define EXPH(scX, bfrX)                                                      \
    do {                                                                       \
      _Pragma("unroll")                                                        \
      for (int s = 0; s < 4; ++s) {                                            \
        half8_t bf;                                                            \
        _Pragma("unroll")                                                      \
        for (int j = 0; j < 8; ++j) {                                          \
          float p = fast_exp2(scX[j & 1][s][j >> 1]);                          \
          lsum2[s] += p;                                                       \
          bf[j] = (_Float16)p;                                                 \
        }                                                                      \
        bfrX[s] = bf;                                                          \
      }                                                                        \
    } while (0)

  // ---- PV accumulate of h-block H from ring buffer BUF with bfrX ----
  #define PVH(bfrX, BUF, H)                                                    \
    do {                                                                       \
      const _Float16* SVB = &sT[BUF][TILEH];                                   \
      _Pragma("unroll")                                                        \
      for (int n = 0; n < 4; ++n) {                                            \
        half8_t vf = *(const half8_t*)&SVB[(n * 16 + l16) * 64 +               \
                                           ((((H) * 4 + quad) ^ hK) << 3)];    \
        _Pragma("unroll")                                                      \
        for (int s = 0; s < 4; ++s)                                            \
          oacc2[n][s] = __builtin_amdgcn_mfma_f32_16x16x32_f16(                \
              vf, bfrX[s], oacc2[n][s], 0, 0, 0);                              \
      }                                                                        \
    } while (0)

  // counted-vmcnt phase gate: my loads older than newest N done + barrier
  // => all waves' data for the gated tile landed. Loads stay in flight.
  #define GATE(N)                                                              \
    do {                                                                       \
      asm volatile("s_waitcnt vmcnt(" #N ")" ::: "memory");                    \
      __builtin_amdgcn_s_barrier();                                            \
      __builtin_amdgcn_sched_barrier(0);                                       \
    } while (0)

  floatx4 scA[2][4], scB[2][4];
  half8_t bfrA[4], bfrB[4];

  // ---------- prologue ----------
  ASYNC(kt0 + 0, 0);
  ASYNC(kt0 + 1, 1);
  GATE(4);                         // tile 0 landed; tile 1 in flight
  ASYNC(kt0 + 2, 2);
  QKH(scA, 0, 0);

  // ---------- pipelined main loop (t = 0 .. KHALF-3) ----------
  // At each GATE: outstanding = tiles t+1, t+2 (8 loads) -> vmcnt(4)
  // guarantees tile t+1; tile t+2 stays in flight across the barrier.
  #pragma unroll 1
  for (int t = 0; t < KHALF - 2; ++t) {
    const int cb = t & 3;
    QKH(scB, cb, 1);               // matrix: tile t, h1
    EXPH(scA, bfrA);               // VALU: overlaps QKH above
    PVH(bfrA, cb, 0);              // matrix: tile t, h0
    GATE(4);
    if (t + 3 < KHALF) ASYNC(kt0 + t + 3, (t + 3) & 3);
    QKH(scA, (t + 1) & 3, 0);      // matrix: tile t+1, h0 (fresh buffer)
    EXPH(scB, bfrB);               // VALU: overlaps QKH above
    PVH(bfrB, cb, 1);              // matrix: tile t, h1 (old buffer -- WAR
                                   // safe: stage target (t+3)&3 != t&3)
  }

  // ---------- epilogue: t = KHALF-2 then KHALF-1 ----------
  {
    const int cb = (KHALF - 2) & 3;
    QKH(scB, cb, 1);
    EXPH(scA, bfrA);
    PVH(bfrA, cb, 0);
    GATE(0);                       // only tile KHALF-1 outstanding: drain it
    QKH(scA, (KHALF - 1) & 3, 0);
    EXPH(scB, bfrB);
    PVH(bfrB, cb, 1);
  }
  {
    const int cb = (KHALF - 1) & 3;
    QKH(scB, cb, 1);
    EXPH(scA, bfrA);
    PVH(bfrA, cb, 0);
    EXPH(scB, bfrB);
    PVH(bfrB, cb, 1);
  }

  // ---------- epilogue: UNNORMALIZED partial O^T + row sums ----------
  #pragma unroll
  for (int s = 0; s < 4; ++s) {
    float v = lsum2[s];
    v += __shfl_xor(v, 16);
    v += __shfl_xor(v, 32);
    if (lane < 16) Ls[s * 16 + l16] = v;
  }
  #pragma unroll
  for (int s = 0; s < 4; ++s)
    #pragma unroll
    for (int n = 0; n < 4; ++n)
      *(floatx4*)&Ob[(s * 16 + l16) * DIM + n * 16 + quad * 4] = oacc2[n][s];

  // ---------- split-K fixup: second finisher of the (b,qt) pair combines ----
  // release: every thread fences its own global stores to agent scope,
  // then thread0 bumps the pair flag (ACQ_REL, agent). old==1 -> we are
  // second: acquire-fence (invalidates stale cross-XCD lines) and combine.
  __threadfence();
  __syncthreads();
  __shared__ unsigned int s_old;
  if (tid == 0)
    s_old = __hip_atomic_fetch_add(&flags[b * (SEQ / BQ) + qt], 1u,
                                   __ATOMIC_ACQ_REL, __HIP_MEMORY_SCOPE_AGENT);
  __syncthreads();
  if (s_old == 1u) {
    __threadfence();
    const size_t rbase = (size_t)b * SEQ + qt * BQ;     // first row of pair
    float*       Of  = O0g + rbase * DIM;
    const float* O1f = O1g + rbase * DIM;
    const float* l0  = lsg + rbase;
    const float* l1  = lsg + NROWS + rbase;
    #pragma unroll 1
    for (int i4 = tid; i4 < (BQ * DIM) / 4; i4 += 256) {  // 4096 float4s
      const int row = i4 >> 4;                            // 16 float4 per row
      const float inv = fast_rcp(l0[row] + l1[row]);
      const float4 a  = ((const float4*)Of)[i4];
      const float4 bb = ((const float4*)O1f)[i4];
      float4 rr;
      rr.x = (a.x + bb.x) * inv;
      rr.y = (a.y + bb.y) * inv;
      rr.z = (a.z + bb.z) * inv;
      rr.w = (a.w + bb.w) * inv;
      ((float4*)Of)[i4] = rr;
    }
  }

  #undef ASYNC
  #undef QKH
  #undef EXPH
  #undef PVH
  #undef GATE
}

extern "C" void kernel_launch(void* const* d_in, const int* in_sizes, int n_in,
                              void* d_out, int out_size, void* d_ws, size_t ws_size,
                              hipStream_t stream) {
  const float* Q = (const float*)d_in[0];
  const float* K = (const float*)d_in[1];
  const float* V = (const float*)d_in[2];
  float* O  = (float*)d_out;
  (void)in_sizes; (void)n_in; (void)out_size; (void)ws_size;

  // ws layout (floats): O1 [OELEMS] | Ls [2*NROWS] | flags [256 u32] |
  //                     Kh,Vh images (f16)
  float*        O1    = (float*)d_ws;
  float*        Ls    = O1 + OELEMS;
  unsigned int* flags = (unsigned int*)(Ls + 2 * NROWS);
  _Float16*     Kh    = (_Float16*)(flags + NPAIR);   // 1KB, 16B-aligned
  _Float16*     Vh    = Kh + (size_t)NTILES * TILEH;
  // total: ~34.1 MB + 1KB (fits: R9 proved >=51 MB)

  hipMemsetAsync(flags, 0, NPAIR * sizeof(unsigned int), stream);
  prepack_kv<<<dim3(NTILES), dim3(256), 0, stream>>>(K, V, Kh, Vh);
  attn_f16_flash<<<dim3(2 * NBATCH * (SEQ / BQ)), dim3(256), 0, stream>>>(
      Q, Kh, Vh, O, O1, Ls, flags);
}

// Round 9
// 163.105 us; speedup vs baseline: 1.5851x; 1.5851x over previous
//
#include <hip/hip_runtime.h>

// Transposed flash attention, f16 MFMA (16x16x32), no-max softmax, NO SPLIT-K.
// R19: R18's fused fixup FAILED (83->185us main): agent-scope __threadfence
// per block forces L2 writeback/invalidate on non-coherent per-XCD L2s ->
// repeatedly evicted the L2-resident K/V images (FETCH 16->33MB, MfmaUtil
// 33->15). Cross-XCD combine inside the hot kernel is structurally poisoned.
// Instead: DELETE split-K. R11/R12 proved occupancy isn't the lever, so the
// grid doubling split-K buys is worthless. Grid 512 = 16b x 32qt, BQ=128,
// s=2 slabs/wave (R12's verified geometry, +3% vs s=4), each block walks all
// 64 K-tiles; each wave then owns its rows' COMPLETE softmax sum ->
// normalize in-register (4 shfl + rcp + muls) and write final O ONCE to
// d_out. Deleted: combine kernel + launch, O1 (33MB traffic), Ls, memset,
// flags, fences. Main-loop structure verbatim from R15/R17 (83.2us,
// verified 2x): 4-ring LDS, GATE(4) counted vmcnt, dual score-state
// exp||MFMA. Numerics: same per-element ops; row sum now single-pass
// (was two partials + add in combine). launch_bounds(256,2) -- NEVER more
// (R9: 7x spill). Null read: total ~163 despite deleted kernel -> the ~81us
// bucket is harness-fixed; main structure is the only lever left.

#define NBATCH 16
#define SEQ    4096
#define DIM    64
#define BQ     128
#define BK     64
#define NKT    (SEQ / BK)      // 64 tiles, full K per block
#define NTILES (NBATCH * NKT)         // 1024
#define TILEH  4096                   // halfs per 64x64 tile image (8 KB)

#define QSCALE 0.180336879f   // 0.125 * log2(e)

typedef _Float16 half2_t __attribute__((ext_vector_type(2)));
typedef _Float16 half4_t __attribute__((ext_vector_type(4)));
typedef _Float16 half8_t __attribute__((ext_vector_type(8)));
typedef float    floatx4 __attribute__((ext_vector_type(4)));

__device__ inline float fast_exp2(float x) {
#if __has_builtin(__builtin_amdgcn_exp2f)
  return __builtin_amdgcn_exp2f(x);
#else
  return exp2f(x);
#endif
}
__device__ inline float fast_rcp(float x) {
#if __has_builtin(__builtin_amdgcn_rcpf)
  return __builtin_amdgcn_rcpf(x);
#else
  return 1.0f / x;
#endif
}

// swizzled offset in halfs for element (row, col) of a 64x64 half tile
__device__ inline int swz(int row, int col) {
  return row * 64 + ((((col >> 3) ^ ((row >> 1) & 7)) << 3) | (col & 7));
}

// async 16B global->LDS copy: lds dest is wave-uniform; HW adds lane*16
__device__ inline void async16(const void* g, void* l) {
  __builtin_amdgcn_global_load_lds(
      (const __attribute__((address_space(1))) void*)g,
      (__attribute__((address_space(3))) void*)l, 16, 0, 0);
}

// ---------------- prepack: K,V f32 -> per-tile f16 LDS images ----------------
__global__ __launch_bounds__(256, 2)
void prepack_kv(const float* __restrict__ Kg, const float* __restrict__ Vg,
                _Float16* __restrict__ Kh, _Float16* __restrict__ Vh)
{
  __shared__ __align__(16) _Float16 sKi[TILEH];
  __shared__ __align__(16) _Float16 sVi[TILEH];
  const int tid = threadIdx.x;
  const int t16 = tid & 15;
  const int kg  = tid >> 4;
  const int bt  = blockIdx.x;                 // b*64 + kt
  const float* Kt_ = Kg + (size_t)bt * BK * DIM;
  const float* Vt_ = Vg + (size_t)bt * BK * DIM;

  floatx4 kbuf[4], vbuf[4];
  #pragma unroll
  for (int i = 0; i < 4; ++i) {
    const int key = kg + 16 * i;
    kbuf[i] = *(const floatx4*)(Kt_ + key * DIM + t16 * 4);
    vbuf[i] = *(const floatx4*)(Vt_ + key * DIM + t16 * 4);
  }
  #pragma unroll
  for (int i = 0; i < 4; ++i) {               // K: [key][dim] swizzled
    const int key = kg + 16 * i;
    half4_t h;
    #pragma unroll
    for (int j = 0; j < 4; ++j) h[j] = (_Float16)kbuf[i][j];
    *(half4_t*)&sKi[swz(key, t16 * 4)] = h;
  }
  {                                           // V: [dim][slot] swizzled
    const int vbase = (kg >> 2) * 8 + (kg & 3) * 2;
    #pragma unroll
    for (int e = 0; e < 4; ++e) {
      const int dim = t16 * 4 + e;
      half2_t h0; h0[0] = (_Float16)vbuf[0][e]; h0[1] = (_Float16)vbuf[1][e];
      half2_t h1; h1[0] = (_Float16)vbuf[2][e]; h1[1] = (_Float16)vbuf[3][e];
      *(half2_t*)&sVi[swz(dim, vbase)]      = h0;
      *(half2_t*)&sVi[swz(dim, vbase + 32)] = h1;
    }
  }
  __syncthreads();
  half8_t* Ko = (half8_t*)(Kh + (size_t)bt * TILEH);
  half8_t* Vo = (half8_t*)(Vh + (size_t)bt * TILEH);
  const half8_t* Ks = (const half8_t*)sKi;
  const half8_t* Vs = (const half8_t*)sVi;
  Ko[tid] = Ks[tid]; Ko[tid + 256] = Ks[tid + 256];
  Vo[tid] = Vs[tid]; Vo[tid + 256] = Vs[tid + 256];
}

// ---------------- main kernel: full-K per block, in-register normalize -----
__global__ __launch_bounds__(256, 2)
void attn_f16_flash(const float* __restrict__ Qg, const _Float16* __restrict__ Kh,
                    const _Float16* __restrict__ Vh, float* __restrict__ Og)
{
  __shared__ __align__(16) _Float16 sT[4][2 * TILEH];  // ring: [buf][ K | V ]

  const int tid  = threadIdx.x;
  const int wave = tid >> 6;
  const int lane = tid & 63;
  const int l16  = lane & 15;
  const int quad = lane >> 4;
  const int hK   = (l16 >> 1) & 7;

  // XCD-clustered decode (bijective over 512 blocks): XCD x = bid&7 gets
  // batches {x, x+8} only -> 2MB K/V image working set per 4MB XCD L2.
  const int bid  = blockIdx.x;
  const int x    = bid & 7;
  const int r    = bid >> 3;                // 0..63
  const int b    = x + ((r & 1) << 3);
  const int qt   = r >> 1;                  // 0..31
  const int q0   = qt * BQ + wave * 32;     // 32 rows per wave

  const float* Qb = Qg + ((size_t)b * SEQ + q0) * DIM;
  float*       Ob = Og + ((size_t)b * SEQ + q0) * DIM;

  // ---- Q fragments (B-operand of S^T = K*Q^T), pre-scaled ----
  half8_t qf[2][2];
  #pragma unroll
  for (int s = 0; s < 2; ++s)
    #pragma unroll
    for (int c = 0; c < 2; ++c) {
      const floatx4 f0 = *(const floatx4*)(Qb + (s * 16 + l16) * DIM + c * 32 + quad * 8);
      const floatx4 f1 = *(const floatx4*)(Qb + (s * 16 + l16) * DIM + c * 32 + quad * 8 + 4);
      half8_t h;
      #pragma unroll
      for (int j = 0; j < 4; ++j) h[j] = (_Float16)(f0[j] * QSCALE);
      #pragma unroll
      for (int j = 0; j < 4; ++j) h[4 + j] = (_Float16)(f1[j] * QSCALE);
      qf[s][c] = h;
    }

  floatx4 oacc2[4][2];   // [dim-tile n][q-slab s]
  float   lsum2[2];
  #pragma unroll
  for (int n = 0; n < 4; ++n)
    #pragma unroll
    for (int s = 0; s < 2; ++s) oacc2[n][s] = (floatx4){0.f, 0.f, 0.f, 0.f};
  #pragma unroll
  for (int s = 0; s < 2; ++s) lsum2[s] = 0.f;

  // ---- async staging: 4 x 16B-per-lane copies per wave per tile ----
  #define ASYNC(KT, BUF)                                                       \
    do {                                                                       \
      const char* gk = (const char*)(Kh + ((size_t)b * NKT + (KT)) * TILEH)    \
                       + wave * 2048;                                          \
      const char* gv = (const char*)(Vh + ((size_t)b * NKT + (KT)) * TILEH)    \
                       + wave * 2048;                                          \
      char* lk = (char*)(&sT[BUF][0])     + wave * 2048;                       \
      char* lv = (char*)(&sT[BUF][TILEH]) + wave * 2048;                       \
      async16(gk + lane * 16,        lk);                                      \
      async16(gk + 1024 + lane * 16, lk + 1024);                               \
      async16(gv + lane * 16,        lv);                                      \
      async16(gv + 1024 + lane * 16, lv + 1024);                               \
    } while (0)

  // ---- QK^T of h-block H from ring buffer BUF into scX ----
  #define QKH(scX, BUF, H)                                                     \
    do {                                                                       \
      const _Float16* SKB = &sT[BUF][0];                                       \
      _Pragma("unroll")                                                        \
      for (int k2 = 0; k2 < 2; ++k2)                                           \
        _Pragma("unroll")                                                      \
        for (int s = 0; s < 2; ++s) scX[k2][s] = (floatx4){0.f, 0.f, 0.f, 0.f};\
      _Pragma("unroll")                                                        \
      for (int k2 = 0; k2 < 2; ++k2) {                                         \
        const int nk = (H) * 2 + k2;                                           \
        _Pragma("unroll")                                                      \
        for (int c = 0; c < 2; ++c) {                                          \
          half8_t kf = *(const half8_t*)&SKB[(nk * 16 + l16) * 64 +            \
                                             (((c * 4 + quad) ^ hK) << 3)];    \
          _Pragma("unroll")                                                    \
          for (int s = 0; s < 2; ++s)                                          \
            scX[k2][s] = __builtin_amdgcn_mfma_f32_16x16x32_f16(               \
                kf, qf[s][c], scX[k2][s], 0, 0, 0);                            \
        }                                                                      \
      }                                                                        \
    } while (0)

  // ---- softmax exp of scX -> bfrX (+ lsum) ----
  #define EXPH(scX, bfrX)                                                      \
    do {                                                                       \
      _Pragma("unroll")                                                        \
      for (int s = 0; s < 2; ++s) {                                            \
        half8_t bf;                                                            \
        _Pragma("unroll")                                                      \
        for (int j = 0; j < 8; ++j) {                                          \
          float p = fast_exp2(scX[j & 1][s][j >> 1]);                          \
          lsum2[s] += p;                                                       \
          bf[j] = (_Float16)p;                                                 \
        }                                                                      \
        bfrX[s] = bf;                                                          \
      }                                                                        \
    } while (0)

  // ---- PV accumulate of h-block H from ring buffer BUF with bfrX ----
  #define PVH(bfrX, BUF, H)                                                    \
    do {                                                                       \
      const _Float16* SVB = &sT[BUF][TILEH];                                   \
      _Pragma("unroll")                                                        \
      for (int n = 0; n < 4; ++n) {                                            \
        half8_t vf = *(const half8_t*)&SVB[(n * 16 + l16) * 64 +               \
                                           ((((H) * 4 + quad) ^ hK) << 3)];    \
        _Pragma("unroll")                                                      \
        for (int s = 0; s < 2; ++s)                                            \
          oacc2[n][s] = __builtin_amdgcn_mfma_f32_16x16x32_f16(                \
              vf, bfrX[s], oacc2[n][s], 0, 0, 0);                              \
      }                                                                        \
    } while (0)

  // counted-vmcnt phase gate: my loads older than newest N done + barrier
  // => all waves' data for the gated tile landed. Loads stay in flight.
  #define GATE(N)                                                              \
    do {                                                                       \
      asm volatile("s_waitcnt vmcnt(" #N ")" ::: "memory");                    \
      __builtin_amdgcn_s_barrier();                                            \
      __builtin_amdgcn_sched_barrier(0);                                       \
    } while (0)

  floatx4 scA[2][2], scB[2][2];
  half8_t bfrA[2], bfrB[2];

  // ---------- prologue ----------
  ASYNC(0, 0);
  ASYNC(1, 1);
  GATE(4);                         // tile 0 landed; tile 1 in flight
  ASYNC(2, 2);
  QKH(scA, 0, 0);

  // ---------- pipelined main loop (t = 0 .. NKT-3) ----------
  // At each GATE: outstanding = tiles t+1, t+2 (8 loads) -> vmcnt(4)
  // guarantees tile t+1; tile t+2 stays in flight across the barrier.
  #pragma unroll 1
  for (int t = 0; t < NKT - 2; ++t) {
    const int cb = t & 3;
    QKH(scB, cb, 1);               // matrix: tile t, h1
    EXPH(scA, bfrA);               // VALU: overlaps QKH above
    PVH(bfrA, cb, 0);              // matrix: tile t, h0
    GATE(4);
    if (t + 3 < NKT) ASYNC(t + 3, (t + 3) & 3);
    QKH(scA, (t + 1) & 3, 0);      // matrix: tile t+1, h0 (fresh buffer)
    EXPH(scB, bfrB);               // VALU: overlaps QKH above
    PVH(bfrB, cb, 1);              // matrix: tile t, h1 (old buffer -- WAR
                                   // safe: stage target (t+3)&3 != t&3)
  }

  // ---------- epilogue: t = NKT-2 then NKT-1 ----------
  {
    const int cb = (NKT - 2) & 3;
    QKH(scB, cb, 1);
    EXPH(scA, bfrA);
    PVH(bfrA, cb, 0);
    GATE(0);                       // only tile NKT-1 outstanding: drain it
    QKH(scA, (NKT - 1) & 3, 0);
    EXPH(scB, bfrB);
    PVH(bfrB, cb, 1);
  }
  {
    const int cb = (NKT - 1) & 3;
    QKH(scB, cb, 1);
    EXPH(scA, bfrA);
    PVH(bfrA, cb, 0);
    EXPH(scB, bfrB);
    PVH(bfrB, cb, 1);
  }

  // ---------- epilogue: in-register normalize + single O write ----------
  // Row of lane's acc elements (slab s): s*16+l16. Quads (lanes l16, +16,
  // +32, +48) hold the same row -> xor16+xor32 gives every lane its full
  // row sum. Math identical to old combine: out = (sum of partials) * rcp.
  #pragma unroll
  for (int s = 0; s < 2; ++s) {
    float v = lsum2[s];
    v += __shfl_xor(v, 16);
    v += __shfl_xor(v, 32);
    const float inv = fast_rcp(v);
    #pragma unroll
    for (int n = 0; n < 4; ++n) {
      floatx4 o = oacc2[n][s];
      #pragma unroll
      for (int j = 0; j < 4; ++j) o[j] *= inv;
      *(floatx4*)&Ob[(s * 16 + l16) * DIM + n * 16 + quad * 4] = o;
    }
  }

  #undef ASYNC
  #undef QKH
  #undef EXPH
  #undef PVH
  #undef GATE
}

extern "C" void kernel_launch(void* const* d_in, const int* in_sizes, int n_in,
                              void* d_out, int out_size, void* d_ws, size_t ws_size,
                              hipStream_t stream) {
  const float* Q = (const float*)d_in[0];
  const float* K = (const float*)d_in[1];
  const float* V = (const float*)d_in[2];
  float* O  = (float*)d_out;
  (void)in_sizes; (void)n_in; (void)out_size; (void)ws_size;

  // ws layout: Kh,Vh images (f16) only. total ~16.8 MB (R9 proved >=51 MB).
  _Float16* Kh = (_Float16*)d_ws;
  _Float16* Vh = Kh + (size_t)NTILES * TILEH;

  prepack_kv<<<dim3(NTILES), dim3(256), 0, stream>>>(K, V, Kh, Vh);
  attn_f16_flash<<<dim3(NBATCH * (SEQ / BQ)), dim3(256), 0, stream>>>(
      Q, Kh, Vh, O);
}

// Round 10
// 162.781 us; speedup vs baseline: 1.5883x; 1.0020x over previous
//
#include <hip/hip_runtime.h>

// Transposed flash attention, f16 MFMA (16x16x32), no-max softmax, NO SPLIT-K.
// R20: main kernel BYTE-IDENTICAL to R19 (best: 84.6us main / 163.1 total,
// verified; 6 structural variants all 83-86us -> plateau of this structure).
// This round optimizes the last untouched kernel: prepack. Old prepack
// staged BOTH K and V through LDS + barrier + dump. Only V needs LDS (it is
// transposed dim-major); the K image is elementwise cvt + permuted store ->
// now stored DIRECTLY to global (each 16-lane group covers one 128B row =
// one cache line, coalesced). Halves prepack LDS traffic, removes K's
// post-barrier store serialization, overlaps K global stores with V LDS
// writes. Image content byte-identical (same swz, same values) -> main
// kernel + numerics bit-identical. Predicted: prepack -3-6us, total
// ~157-160. Null read (flat 163): non-main is harness-fixed; plateau stands.

#define NBATCH 16
#define SEQ    4096
#define DIM    64
#define BQ     128
#define BK     64
#define NKT    (SEQ / BK)      // 64 tiles, full K per block
#define NTILES (NBATCH * NKT)         // 1024
#define TILEH  4096                   // halfs per 64x64 tile image (8 KB)

#define QSCALE 0.180336879f   // 0.125 * log2(e)

typedef _Float16 half2_t __attribute__((ext_vector_type(2)));
typedef _Float16 half4_t __attribute__((ext_vector_type(4)));
typedef _Float16 half8_t __attribute__((ext_vector_type(8)));
typedef float    floatx4 __attribute__((ext_vector_type(4)));

__device__ inline float fast_exp2(float x) {
#if __has_builtin(__builtin_amdgcn_exp2f)
  return __builtin_amdgcn_exp2f(x);
#else
  return exp2f(x);
#endif
}
__device__ inline float fast_rcp(float x) {
#if __has_builtin(__builtin_amdgcn_rcpf)
  return __builtin_amdgcn_rcpf(x);
#else
  return 1.0f / x;
#endif
}

// swizzled offset in halfs for element (row, col) of a 64x64 half tile
__device__ inline int swz(int row, int col) {
  return row * 64 + ((((col >> 3) ^ ((row >> 1) & 7)) << 3) | (col & 7));
}

// async 16B global->LDS copy: lds dest is wave-uniform; HW adds lane*16
__device__ inline void async16(const void* g, void* l) {
  __builtin_amdgcn_global_load_lds(
      (const __attribute__((address_space(1))) void*)g,
      (__attribute__((address_space(3))) void*)l, 16, 0, 0);
}

// ---------------- prepack: K,V f32 -> per-tile f16 images ----------------
// R20: K converted + stored DIRECT to global (no LDS, no barrier dep);
// V transposed through LDS as before. Image bytes identical to R19's.
__global__ __launch_bounds__(256, 2)
void prepack_kv(const float* __restrict__ Kg, const float* __restrict__ Vg,
                _Float16* __restrict__ Kh, _Float16* __restrict__ Vh)
{
  __shared__ __align__(16) _Float16 sVi[TILEH];
  const int tid = threadIdx.x;
  const int t16 = tid & 15;
  const int kg  = tid >> 4;
  const int bt  = blockIdx.x;                 // b*64 + kt
  const float* Kt_ = Kg + (size_t)bt * BK * DIM;
  const float* Vt_ = Vg + (size_t)bt * BK * DIM;

  floatx4 kbuf[4], vbuf[4];
  #pragma unroll
  for (int i = 0; i < 4; ++i) {
    const int key = kg + 16 * i;
    kbuf[i] = *(const floatx4*)(Kt_ + key * DIM + t16 * 4);
    vbuf[i] = *(const floatx4*)(Vt_ + key * DIM + t16 * 4);
  }
  {                                           // V: [dim][slot] swizzled -> LDS
    const int vbase = (kg >> 2) * 8 + (kg & 3) * 2;
    #pragma unroll
    for (int e = 0; e < 4; ++e) {
      const int dim = t16 * 4 + e;
      half2_t h0; h0[0] = (_Float16)vbuf[0][e]; h0[1] = (_Float16)vbuf[1][e];
      half2_t h1; h1[0] = (_Float16)vbuf[2][e]; h1[1] = (_Float16)vbuf[3][e];
      *(half2_t*)&sVi[swz(dim, vbase)]      = h0;
      *(half2_t*)&sVi[swz(dim, vbase + 32)] = h1;
    }
  }
  {                                           // K: [key][dim] swizzled -> global
    _Float16* Ko = Kh + (size_t)bt * TILEH;   // (overlaps other waves' V LDS)
    #pragma unroll
    for (int i = 0; i < 4; ++i) {
      const int key = kg + 16 * i;
      half4_t h;
      #pragma unroll
      for (int j = 0; j < 4; ++j) h[j] = (_Float16)kbuf[i][j];
      *(half4_t*)&Ko[swz(key, t16 * 4)] = h;  // 16 lanes = one 128B row
    }
  }
  __syncthreads();
  half8_t* Vo = (half8_t*)(Vh + (size_t)bt * TILEH);
  const half8_t* Vs = (const half8_t*)sVi;
  Vo[tid] = Vs[tid]; Vo[tid + 256] = Vs[tid + 256];
}

// ---------------- main kernel: full-K per block, in-register normalize -----
// (byte-identical to R19 -- verified best)
__global__ __launch_bounds__(256, 2)
void attn_f16_flash(const float* __restrict__ Qg, const _Float16* __restrict__ Kh,
                    const _Float16* __restrict__ Vh, float* __restrict__ Og)
{
  __shared__ __align__(16) _Float16 sT[4][2 * TILEH];  // ring: [buf][ K | V ]

  const int tid  = threadIdx.x;
  const int wave = tid >> 6;
  const int lane = tid & 63;
  const int l16  = lane & 15;
  const int quad = lane >> 4;
  const int hK   = (l16 >> 1) & 7;

  // XCD-clustered decode (bijective over 512 blocks): XCD x = bid&7 gets
  // batches {x, x+8} only -> 2MB K/V image working set per 4MB XCD L2.
  const int bid  = blockIdx.x;
  const int x    = bid & 7;
  const int r    = bid >> 3;                // 0..63
  const int b    = x + ((r & 1) << 3);
  const int qt   = r >> 1;                  // 0..31
  const int q0   = qt * BQ + wave * 32;     // 32 rows per wave

  const float* Qb = Qg + ((size_t)b * SEQ + q0) * DIM;
  float*       Ob = Og + ((size_t)b * SEQ + q0) * DIM;

  // ---- Q fragments (B-operand of S^T = K*Q^T), pre-scaled ----
  half8_t qf[2][2];
  #pragma unroll
  for (int s = 0; s < 2; ++s)
    #pragma unroll
    for (int c = 0; c < 2; ++c) {
      const floatx4 f0 = *(const floatx4*)(Qb + (s * 16 + l16) * DIM + c * 32 + quad * 8);
      const floatx4 f1 = *(const floatx4*)(Qb + (s * 16 + l16) * DIM + c * 32 + quad * 8 + 4);
      half8_t h;
      #pragma unroll
      for (int j = 0; j < 4; ++j) h[j] = (_Float16)(f0[j] * QSCALE);
      #pragma unroll
      for (int j = 0; j < 4; ++j) h[4 + j] = (_Float16)(f1[j] * QSCALE);
      qf[s][c] = h;
    }

  floatx4 oacc2[4][2];   // [dim-tile n][q-slab s]
  float   lsum2[2];
  #pragma unroll
  for (int n = 0; n < 4; ++n)
    #pragma unroll
    for (int s = 0; s < 2; ++s) oacc2[n][s] = (floatx4){0.f, 0.f, 0.f, 0.f};
  #pragma unroll
  for (int s = 0; s < 2; ++s) lsum2[s] = 0.f;

  // ---- async staging: 4 x 16B-per-lane copies per wave per tile ----
  #define ASYNC(KT, BUF)                                                       \
    do {                                                                       \
      const char* gk = (const char*)(Kh + ((size_t)b * NKT + (KT)) * TILEH)    \
                       + wave * 2048;                                          \
      const char* gv = (const char*)(Vh + ((size_t)b * NKT + (KT)) * TILEH)    \
                       + wave * 2048;                                          \
      char* lk = (char*)(&sT[BUF][0])     + wave * 2048;                       \
      char* lv = (char*)(&sT[BUF][TILEH]) + wave * 2048;                       \
      async16(gk + lane * 16,        lk);                                      \
      async16(gk + 1024 + lane * 16, lk + 1024);                               \
      async16(gv + lane * 16,        lv);                                      \
      async16(gv + 1024 + lane * 16, lv + 1024);                               \
    } while (0)

  // ---- QK^T of h-block H from ring buffer BUF into scX ----
  #define QKH(scX, BUF, H)                                                     \
    do {                                                                       \
      const _Float16* SKB = &sT[BUF][0];                                       \
      _Pragma("unroll")                                                        \
      for (int k2 = 0; k2 < 2; ++k2)                                           \
        _Pragma("unroll")                                                      \
        for (int s = 0; s < 2; ++s) scX[k2][s] = (floatx4){0.f, 0.f, 0.f, 0.f};\
      _Pragma("unroll")                                                        \
      for (int k2 = 0; k2 < 2; ++k2) {                                         \
        const int nk = (H) * 2 + k2;                                           \
        _Pragma("unroll")                                                      \
        for (int c = 0; c < 2; ++c) {                                          \
          half8_t kf = *(const half8_t*)&SKB[(nk * 16 + l16) * 64 +            \
                                             (((c * 4 + quad) ^ hK) << 3)];    \
          _Pragma("unroll")                                                    \
          for (int s = 0; s < 2; ++s)                                          \
            scX[k2][s] = __builtin_amdgcn_mfma_f32_16x16x32_f16(               \
                kf, qf[s][c], scX[k2][s], 0, 0, 0);                            \
        }                                                                      \
      }                                                                        \
    } while (0)

  // ---- softmax exp of scX -> bfrX (+ lsum) ----
  #define EXPH(scX, bfrX)                                                      \
    do {                                                                       \
      _Pragma("unroll")                                                        \
      for (int s = 0; s < 2; ++s) {                                            \
        half8_t bf;                                                            \
        _Pragma("unroll")                                                      \
        for (int j = 0; j < 8; ++j) {                                          \
          float p = fast_exp2(scX[j & 1][s][j >> 1]);                          \
          lsum2[s] += p;                                                       \
          bf[j] = (_Float16)p;                                                 \
        }                                                                      \
        bfrX[s] = bf;                                                          \
      }                                                                        \
    } while (0)

  // ---- PV accumulate of h-block H from ring buffer BUF with bfrX ----
  #define PVH(bfrX, BUF, H)                                                    \
    do {                                                                       \
      const _Float16* SVB = &sT[BUF][TILEH];                                   \
      _Pragma("unroll")                                                        \
      for (int n = 0; n < 4; ++n) {                                            \
        half8_t vf = *(const half8_t*)&SVB[(n * 16 + l16) * 64 +               \
                                           ((((H) * 4 + quad) ^ hK) << 3)];    \
        _Pragma("unroll")                                                      \
        for (int s = 0; s < 2; ++s)                                            \
          oacc2[n][s] = __builtin_amdgcn_mfma_f32_16x16x32_f16(                \
              vf, bfrX[s], oacc2[n][s], 0, 0, 0);                              \
      }                                                                        \
    } while (0)

  // counted-vmcnt phase gate: my loads older than newest N done + barrier
  // => all waves' data for the gated tile landed. Loads stay in flight.
  #define GATE(N)                                                              \
    do {                                                                       \
      asm volatile("s_waitcnt vmcnt(" #N ")" ::: "memory");                    \
      __builtin_amdgcn_s_barrier();                                            \
      __builtin_amdgcn_sched_barrier(0);                                       \
    } while (0)

  floatx4 scA[2][2], scB[2][2];
  half8_t bfrA[2], bfrB[2];

  // ---------- prologue ----------
  ASYNC(0, 0);
  ASYNC(1, 1);
  GATE(4);                         // tile 0 landed; tile 1 in flight
  ASYNC(2, 2);
  QKH(scA, 0, 0);

  // ---------- pipelined main loop (t = 0 .. NKT-3) ----------
  // At each GATE: outstanding = tiles t+1, t+2 (8 loads) -> vmcnt(4)
  // guarantees tile t+1; tile t+2 stays in flight across the barrier.
  #pragma unroll 1
  for (int t = 0; t < NKT - 2; ++t) {
    const int cb = t & 3;
    QKH(scB, cb, 1);               // matrix: tile t, h1
    EXPH(scA, bfrA);               // VALU: overlaps QKH above
    PVH(bfrA, cb, 0);              // matrix: tile t, h0
    GATE(4);
    if (t + 3 < NKT) ASYNC(t + 3, (t + 3) & 3);
    QKH(scA, (t + 1) & 3, 0);      // matrix: tile t+1, h0 (fresh buffer)
    EXPH(scB, bfrB);               // VALU: overlaps QKH above
    PVH(bfrB, cb, 1);              // matrix: tile t, h1 (old buffer -- WAR
                                   // safe: stage target (t+3)&3 != t&3)
  }

  // ---------- epilogue: t = NKT-2 then NKT-1 ----------
  {
    const int cb = (NKT - 2) & 3;
    QKH(scB, cb, 1);
    EXPH(scA, bfrA);
    PVH(bfrA, cb, 0);
    GATE(0);                       // only tile NKT-1 outstanding: drain it
    QKH(scA, (NKT - 1) & 3, 0);
    EXPH(scB, bfrB);
    PVH(bfrB, cb, 1);
  }
  {
    const int cb = (NKT - 1) & 3;
    QKH(scB, cb, 1);
    EXPH(scA, bfrA);
    PVH(bfrA, cb, 0);
    EXPH(scB, bfrB);
    PVH(bfrB, cb, 1);
  }

  // ---------- epilogue: in-register normalize + single O write ----------
  // Row of lane's acc elements (slab s): s*16+l16. Quads (lanes l16, +16,
  // +32, +48) hold the same row -> xor16+xor32 gives every lane its full
  // row sum. Math identical to old combine: out = (sum of partials) * rcp.
  #pragma unroll
  for (int s = 0; s < 2; ++s) {
    float v = lsum2[s];
    v += __shfl_xor(v, 16);
    v += __shfl_xor(v, 32);
    const float inv = fast_rcp(v);
    #pragma unroll
    for (int n = 0; n < 4; ++n) {
      floatx4 o = oacc2[n][s];
      #pragma unroll
      for (int j = 0; j < 4; ++j) o[j] *= inv;
      *(floatx4*)&Ob[(s * 16 + l16) * DIM + n * 16 + quad * 4] = o;
    }
  }

  #undef ASYNC
  #undef QKH
  #undef EXPH
  #undef PVH
  #undef GATE
}

extern "C" void kernel_launch(void* const* d_in, const int* in_sizes, int n_in,
                              void* d_out, int out_size, void* d_ws, size_t ws_size,
                              hipStream_t stream) {
  const float* Q = (const float*)d_in[0];
  const float* K = (const float*)d_in[1];
  const float* V = (const float*)d_in[2];
  float* O  = (float*)d_out;
  (void)in_sizes; (void)n_in; (void)out_size; (void)ws_size;

  // ws layout: Kh,Vh images (f16) only. total ~16.8 MB (R9 proved >=51 MB).
  _Float16* Kh = (_Float16*)d_ws;
  _Float16* Vh = Kh + (size_t)NTILES * TILEH;

  prepack_kv<<<dim3(NTILES), dim3(256), 0, stream>>>(K, V, Kh, Vh);
  attn_f16_flash<<<dim3(NBATCH * (SEQ / BQ)), dim3(256), 0, stream>>>(
      Q, Kh, Vh, O);
}